// Round 9
// baseline (516.678 us; speedup 1.0000x reference)
//
#include <hip/hip_runtime.h>
#include <hip/hip_fp16.h>
#include <math.h>

// Problem constants (match reference)
constexpr int N_NODES = 65536;
constexpr int N_EDGES = 2097152;
constexpr int F_IN    = 128;
constexpr int H_DIM   = 256;
constexpr int O_DIM   = 128;
constexpr int N_GRAPH = 256;
constexpr int V_SIZE  = 1000;

// 256 buckets of 256 nodes (bucket = col>>8); 256 edge-blocks of 8192 edges.
constexpr int EPB  = 8192;
constexpr int NBLK = N_EDGES / EPB;   // 256
constexpr float FXP = 16777216.0f;    // 2^24

// ---------------- init: pool=0, cf16 convert; block 0 also does graph counts

__global__ void k_init(float* __restrict__ pool, const float* __restrict__ cf,
                       __half* __restrict__ cf16, const int* __restrict__ batch,
                       float* __restrict__ cntf) {
    int i = blockIdx.x * blockDim.x + threadIdx.x;
    if (i < N_GRAPH * O_DIM) pool[i] = 0.0f;
    if (i < V_SIZE * F_IN) cf16[i] = __float2half(cf[i]);
    int i2 = i + N_NODES;
    if (i2 < V_SIZE * F_IN) cf16[i2] = __float2half(cf[i2]);
    if (blockIdx.x == 0) {
        // batch_index is sorted: counts via binary search, no atomics
        int g = threadIdx.x;
        int lo = 0, hi = N_NODES;
        while (lo < hi) { int m = (lo + hi) >> 1; if (batch[m] < g) lo = m + 1; else hi = m; }
        int start = lo;
        lo = 0; hi = N_NODES;
        while (lo < hi) { int m = (lo + hi) >> 1; if (batch[m] <= g) lo = m + 1; else hi = m; }
        cntf[g] = (float)(lo - start);
    }
}

// ---------------- stage A: per-block bucket histogram (LDS) ----------------

__global__ void k_hist(const int* __restrict__ col, int* __restrict__ hist) {
    __shared__ int h[256];
    int t = threadIdx.x;
    h[t] = 0;
    __syncthreads();
    int base = blockIdx.x * EPB;
    #pragma unroll
    for (int i = 0; i < EPB / 256; ++i)
        atomicAdd(&h[col[base + i * 256 + t] >> 8], 1);
    __syncthreads();
    hist[t * NBLK + blockIdx.x] = h[t];   // bucket-major for the scan
}

// ---------------- scan (partial per-256-chunk + block sums) ----------------
// scan3 is folded into k_part/k_build via bsum[] lookups.

__global__ void k_scan1(const int* __restrict__ in, int* __restrict__ out,
                        int* __restrict__ bsum) {
    __shared__ int s[256];
    int tid = threadIdx.x;
    int i = blockIdx.x * 256 + tid;
    int v = in[i];
    s[tid] = v;
    __syncthreads();
    for (int d = 1; d < 256; d <<= 1) {
        int t = (tid >= d) ? s[tid - d] : 0;
        __syncthreads();
        s[tid] += t;
        __syncthreads();
    }
    out[i] = s[tid] - v;
    if (tid == 255) bsum[blockIdx.x] = s[255];
}

__global__ void k_scan2(int* __restrict__ bsum) {
    __shared__ int s[256];
    int tid = threadIdx.x;
    int v = bsum[tid];
    s[tid] = v;
    __syncthreads();
    for (int d = 1; d < 256; d <<= 1) {
        int t = (tid >= d) ? s[tid - d] : 0;
        __syncthreads();
        s[tid] += t;
        __syncthreads();
    }
    bsum[tid] = s[tid] - v;
}

// ---------------- stage C: partition into int2 records (LDS cursors) --------
// rec.x = src:16 | dst8:8 | vocab_hi:8 ; rec.y = vocab_lo:2<<16 | ew_fp16:16

__global__ void k_part(const int* __restrict__ row, const int* __restrict__ col,
                       const float* __restrict__ ew, const int* __restrict__ nidx,
                       const int* __restrict__ hoffs, const int* __restrict__ bsum,
                       int2* __restrict__ part) {
    __shared__ int cur[256];
    int t = threadIdx.x;
    cur[t] = hoffs[t * NBLK + blockIdx.x] + bsum[t];
    __syncthreads();
    int base = blockIdx.x * EPB;
    for (int i = 0; i < EPB / 256; ++i) {
        int e = base + i * 256 + t;
        int r = row[e], c = col[e];
        unsigned hw = (unsigned)__half_as_ushort(__float2half(ew[e]));
        int vb = nidx[r];
        int slot = atomicAdd(&cur[c >> 8], 1);
        int2 rec;
        rec.x = (r << 16) | ((c & 255) << 8) | (vb >> 2);
        rec.y = (int)(((unsigned)(vb & 3) << 16) | hw);
        part[slot] = rec;
    }
}

// ---------------- stage D: per-bucket deg/dis + offs + final CSR ------------
// csr.x = src<<10 | vocab ; csr.y = ew (float).  dis[src] applied in agg.

__global__ void k_build(const int* __restrict__ hoffs, const int* __restrict__ bsum,
                        const int2* __restrict__ part, int2* __restrict__ csr,
                        float* __restrict__ dis, int* __restrict__ offs) {
    __shared__ unsigned long long dc[256];
    __shared__ int sc[256];
    __shared__ int cur[256];
    int t = threadIdx.x;
    int bucket = blockIdx.x;
    dc[t] = 0ULL;
    __syncthreads();
    int start = hoffs[bucket * NBLK] + bsum[bucket];
    int end   = (bucket == 255) ? N_EDGES : (hoffs[(bucket + 1) * NBLK] + bsum[bucket + 1]);
    for (int j = start + t; j < end; j += 256) {
        int2 rec = part[j];
        int dst = (rec.x >> 8) & 255;
        float w = __half2float(__ushort_as_half((unsigned short)(rec.y & 0xFFFF)));
        unsigned long long add = (1ULL << 40) |
            (unsigned long long)(unsigned)(w * FXP + 0.5f);
        atomicAdd(&dc[dst], add);
    }
    __syncthreads();
    unsigned long long v = dc[t];
    float deg = 1.0f + (float)(v & 0xFFFFFFFFFFULL) * (1.0f / FXP);   // self-loop +1
    dis[bucket * 256 + t] = 1.0f / sqrtf(deg);                        // deg >= 1
    int cnt = (int)(v >> 40);
    sc[t] = cnt;
    __syncthreads();
    for (int d = 1; d < 256; d <<= 1) {
        int x = (t >= d) ? sc[t - d] : 0;
        __syncthreads();
        sc[t] += x;
        __syncthreads();
    }
    int node_off = start + sc[t] - cnt;
    offs[bucket * 256 + t] = node_off;
    cur[t] = node_off;
    if (bucket == 255 && t == 255) offs[N_NODES] = N_EDGES;
    __syncthreads();
    for (int j = start + t; j < end; j += 256) {
        int2 rec = part[j];
        int dst = (rec.x >> 8) & 255;
        unsigned src = ((unsigned)rec.x) >> 16;
        int vb = ((rec.x & 255) << 2) | ((rec.y >> 16) & 3);
        float w = __half2float(__ushort_as_half((unsigned short)(rec.y & 0xFFFF)));
        int slot = atomicAdd(&cur[dst], 1);
        int2 e;
        e.x = (int)((src << 10) | (unsigned)vb);
        e.y = __float_as_int(w);
        csr[slot] = e;
    }
}

// ---------------- layer-1 aggregation (wave/node, unroll 16, dis in-loop) ----

__global__ void k_agg0(const __half2* __restrict__ cf16, const int* __restrict__ nidx,
                       const float* __restrict__ dis, const int* __restrict__ offs,
                       const int2* __restrict__ csr, float2* __restrict__ aggX) {
    int wave = threadIdx.x >> 6;
    int lane = threadIdx.x & 63;
    int c = blockIdx.x * 4 + wave;
    float d = dis[c];
    float2 self = __half22float2(cf16[(size_t)nidx[c] * 64 + lane]);
    float2 esum = {0.f, 0.f};
    int s0 = offs[c], s1 = offs[c + 1];
    int s = s0;
    for (; s + 16 <= s1; s += 16) {
        int2 e[16];
        #pragma unroll
        for (int u = 0; u < 16; ++u) e[u] = csr[s + u];
        float dsv[16];
        float2 v[16];
        #pragma unroll
        for (int u = 0; u < 16; ++u) {
            dsv[u] = dis[e[u].x >> 10];
            v[u] = __half22float2(cf16[(size_t)(e[u].x & 1023) * 64 + lane]);
        }
        #pragma unroll
        for (int u = 0; u < 16; ++u) {
            float n = dsv[u] * __int_as_float(e[u].y);
            esum.x += v[u].x * n; esum.y += v[u].y * n;
        }
    }
    for (; s < s1; ++s) {
        int2 e0 = csr[s];
        float n = dis[e0.x >> 10] * __int_as_float(e0.y);
        float2 v0 = __half22float2(cf16[(size_t)(e0.x & 1023) * 64 + lane]);
        esum.x += v0.x * n; esum.y += v0.y * n;
    }
    float dd = d * d;
    float2 acc;
    acc.x = self.x * dd + d * esum.x;
    acc.y = self.y * dd + d * esum.y;
    aggX[(size_t)c * 64 + lane] = acc;
}

// ---------------- GEMM1: aggX [N,128] @ W1 + b1, relu -> h1 [N,256] ----------

__global__ void k_gemm1(const float* __restrict__ aggX, const float* __restrict__ W1,
                        const float* __restrict__ b1, float* __restrict__ h1) {
    __shared__ float xs[32 * F_IN];   // 16 KB
    int nb = blockIdx.x * 32;
    int t  = threadIdx.x;
    const float4* src = (const float4*)(aggX + (size_t)nb * F_IN);
    float4* dst = (float4*)xs;
    #pragma unroll
    for (int p = 0; p < 4; ++p) dst[p * 256 + t] = src[p * 256 + t];
    __syncthreads();
    int o  = t & 63;
    int jg = t >> 6;
    const float* xsj = xs + jg * 8 * F_IN;
    float acc[8][4] = {};
    for (int k = 0; k < F_IN; ++k) {
        float w0 = W1[k * H_DIM + o];
        float w1 = W1[k * H_DIM + o + 64];
        float w2 = W1[k * H_DIM + o + 128];
        float w3 = W1[k * H_DIM + o + 192];
        #pragma unroll
        for (int j = 0; j < 8; ++j) {
            float x = xsj[j * F_IN + k];
            acc[j][0] += x * w0; acc[j][1] += x * w1;
            acc[j][2] += x * w2; acc[j][3] += x * w3;
        }
    }
    float bb0 = b1[o], bb1 = b1[o + 64], bb2 = b1[o + 128], bb3 = b1[o + 192];
    #pragma unroll
    for (int j = 0; j < 8; ++j) {
        size_t base = (size_t)(nb + jg * 8 + j) * H_DIM + o;
        float v0 = acc[j][0] + bb0, v1 = acc[j][1] + bb1;
        float v2 = acc[j][2] + bb2, v3 = acc[j][3] + bb3;
        h1[base]       = v0 > 0.f ? v0 : 0.f;
        h1[base + 64]  = v1 > 0.f ? v1 : 0.f;
        h1[base + 128] = v2 > 0.f ? v2 : 0.f;
        h1[base + 192] = v3 > 0.f ? v3 : 0.f;
    }
}

// ---------------- GEMM2: h1 [N,256] @ W2 -> xw2 (fp16) [N,128] ---------------

__global__ void k_gemm2(const float* __restrict__ h1, const float* __restrict__ W2,
                        __half* __restrict__ xw2h) {
    __shared__ float xs[32 * H_DIM];  // 32 KB
    int nb = blockIdx.x * 32;
    int t  = threadIdx.x;
    const float4* src = (const float4*)(h1 + (size_t)nb * H_DIM);
    float4* dst = (float4*)xs;
    #pragma unroll
    for (int p = 0; p < 8; ++p) dst[p * 256 + t] = src[p * 256 + t];
    __syncthreads();
    int o  = t & 63;
    int jg = t >> 6;
    const float* xsj = xs + jg * 8 * H_DIM;
    float acc[8][2] = {};
    for (int k = 0; k < H_DIM; ++k) {
        float w0 = W2[k * O_DIM + o];
        float w1 = W2[k * O_DIM + o + 64];
        #pragma unroll
        for (int j = 0; j < 8; ++j) {
            float x = xsj[j * H_DIM + k];
            acc[j][0] += x * w0; acc[j][1] += x * w1;
        }
    }
    #pragma unroll
    for (int j = 0; j < 8; ++j) {
        size_t base = (size_t)(nb + jg * 8 + j) * O_DIM + o;
        xw2h[base]      = __float2half(acc[j][0]);
        xw2h[base + 64] = __float2half(acc[j][1]);
    }
}

// ---------------- layer-2 agg + relu + LDS-reduced pool (4 nodes/block) ------

__global__ void k_agg2_pool(const __half2* __restrict__ xw2h, const float* __restrict__ b2,
                            const float* __restrict__ dis, const int* __restrict__ offs,
                            const int2* __restrict__ csr, const int* __restrict__ batch,
                            float* __restrict__ pool) {
    __shared__ float2 red[4][64];
    __shared__ int bgs[4];
    int wave = threadIdx.x >> 6;
    int lane = threadIdx.x & 63;
    int c = blockIdx.x * 4 + wave;
    float d = dis[c];
    float2 self = __half22float2(xw2h[(size_t)c * 64 + lane]);
    float2 bb = ((const float2*)b2)[lane];
    float2 esum = {0.f, 0.f};
    int s0 = offs[c], s1 = offs[c + 1];
    int s = s0;
    for (; s + 16 <= s1; s += 16) {
        int2 e[16];
        #pragma unroll
        for (int u = 0; u < 16; ++u) e[u] = csr[s + u];
        float dsv[16];
        float2 v[16];
        #pragma unroll
        for (int u = 0; u < 16; ++u) {
            dsv[u] = dis[e[u].x >> 10];
            v[u] = __half22float2(xw2h[(size_t)(e[u].x >> 10) * 64 + lane]);
        }
        #pragma unroll
        for (int u = 0; u < 16; ++u) {
            float n = dsv[u] * __int_as_float(e[u].y);
            esum.x += v[u].x * n; esum.y += v[u].y * n;
        }
    }
    for (; s < s1; ++s) {
        int2 e0 = csr[s];
        float n = dis[e0.x >> 10] * __int_as_float(e0.y);
        float2 v0 = __half22float2(xw2h[(size_t)(e0.x >> 10) * 64 + lane]);
        esum.x += v0.x * n; esum.y += v0.y * n;
    }
    float dd = d * d;
    float2 acc;
    acc.x = bb.x + self.x * dd + d * esum.x;
    acc.y = bb.y + self.y * dd + d * esum.y;
    acc.x = acc.x > 0.0f ? acc.x : 0.0f;
    acc.y = acc.y > 0.0f ? acc.y : 0.0f;
    red[wave][lane] = acc;
    if (lane == 0) bgs[wave] = batch[c];
    __syncthreads();
    if (wave == 0) {
        float2 a = red[0][lane];
        int cg = bgs[0];
        #pragma unroll
        for (int w = 1; w < 4; ++w) {
            int g = bgs[w];
            float2 r = red[w][lane];
            if (g == cg) { a.x += r.x; a.y += r.y; }
            else {
                atomicAdd(&pool[cg * O_DIM + 2 * lane], a.x);
                atomicAdd(&pool[cg * O_DIM + 2 * lane + 1], a.y);
                a = r; cg = g;
            }
        }
        atomicAdd(&pool[cg * O_DIM + 2 * lane], a.x);
        atomicAdd(&pool[cg * O_DIM + 2 * lane + 1], a.y);
    }
}

__global__ void k_final(const float* __restrict__ pool, const float* __restrict__ cnt,
                        float* __restrict__ out) {
    int t = blockIdx.x * blockDim.x + threadIdx.x;
    if (t < N_GRAPH * O_DIM) {
        int g = t / O_DIM;
        out[t] = pool[t] / fmaxf(cnt[g], 1.0f);
    }
}

// ---------------- launch ----------------

extern "C" void kernel_launch(void* const* d_in, const int* in_sizes, int n_in,
                              void* d_out, int out_size, void* d_ws, size_t ws_size,
                              hipStream_t stream) {
    const float* cf   = (const float*)d_in[0];   // [V,128]
    const float* W1   = (const float*)d_in[1];   // [128,256]
    const float* b1   = (const float*)d_in[2];   // [256]
    const float* W2   = (const float*)d_in[3];   // [256,128]
    const float* b2   = (const float*)d_in[4];   // [128]
    const float* ew   = (const float*)d_in[5];   // [E]
    const int*   nidx = (const int*)d_in[6];     // [N]
    const int*   eidx = (const int*)d_in[7];     // [2,E]
    const int*   bidx = (const int*)d_in[8];     // [N]
    float* out = (float*)d_out;

    const int* row = eidx;            // source
    const int* col = eidx + N_EDGES;  // target

    // workspace layout (bytes)
    char* ws = (char*)d_ws;
    size_t off = 0;
    int*   hist  = (int*)  (ws + off); off += (size_t)N_NODES * 4;          // 256K
    int*   hoffs = (int*)  (ws + off); off += (size_t)N_NODES * 4;          // 256K
    int*   bsum  = (int*)  (ws + off); off += 4096;
    float* dis   = (float*)(ws + off); off += (size_t)N_NODES * 4;          // 256K
    int*   offs  = (int*)  (ws + off); off += (size_t)(N_NODES + 16) * 4;   // 256K
    int2*  csr   = (int2*) (ws + off); off += (size_t)N_EDGES * 8;          // 16M
    float* pool  = (float*)(ws + off); off += (size_t)(N_GRAPH * O_DIM + N_GRAPH) * 4;
    __half* cf16 = (__half*)(ws + off); off += (size_t)V_SIZE * F_IN * 2;   // 256K
    off = (off + 255) & ~(size_t)255;
    float* aggX  = (float*)(ws + off); off += (size_t)N_NODES * F_IN * 4;   // 32M
    float* h1    = (float*)(ws + off);                                      // 64M
    int2*  part  = (int2*)aggX;      // 16M bucket buffer, dead before k_agg0
    __half* xw2h = (__half*)aggX;    // aggX dead after gemm1
    float* cntf  = pool + N_GRAPH * O_DIM;

    // 1. init (+gcount in block 0) + bucket histogram + 2-stage scan
    k_init<<<N_NODES / 256, 256, 0, stream>>>(pool, cf, cf16, bidx, cntf);
    k_hist<<<NBLK, 256, 0, stream>>>(col, hist);
    k_scan1<<<256, 256, 0, stream>>>(hist, hoffs, bsum);
    k_scan2<<<1, 256, 0, stream>>>(bsum);

    // 2. partition (int2 recs) -> per-bucket build (deg/dis/offs/CSR)
    k_part<<<NBLK, 256, 0, stream>>>(row, col, ew, nidx, hoffs, bsum, part);
    k_build<<<256, 256, 0, stream>>>(hoffs, bsum, part, csr, dis, offs);

    // 3. layer 1: aggregate fp16 features (wave/node), then GEMM (+b1, relu)
    k_agg0<<<N_NODES / 4, 256, 0, stream>>>((const __half2*)cf16, nidx, dis, offs, csr,
                                            (float2*)aggX);
    k_gemm1<<<N_NODES / 32, 256, 0, stream>>>(aggX, W1, b1, h1);

    // 4. layer 2: GEMM -> fp16, aggregate + relu + LDS-reduced pool
    k_gemm2<<<N_NODES / 32, 256, 0, stream>>>(h1, W2, xw2h);
    k_agg2_pool<<<N_NODES / 4, 256, 0, stream>>>((const __half2*)xw2h, b2, dis, offs, csr,
                                                 bidx, pool);

    // 5. final divide
    k_final<<<(N_GRAPH * O_DIM + 255) / 256, 256, 0, stream>>>(pool, cntf, out);
}

// Round 10
// 443.415 us; speedup vs baseline: 1.1652x; 1.1652x over previous
//
#include <hip/hip_runtime.h>
#include <hip/hip_fp16.h>
#include <math.h>

// Problem constants (match reference)
constexpr int N_NODES = 65536;
constexpr int N_EDGES = 2097152;
constexpr int F_IN    = 128;
constexpr int H_DIM   = 256;
constexpr int O_DIM   = 128;
constexpr int N_GRAPH = 256;
constexpr int V_SIZE  = 1000;

// 256 buckets of 256 nodes (bucket = col>>8); 256 edge-blocks of 8192 edges.
constexpr int EPB  = 8192;
constexpr int NBLK = N_EDGES / EPB;   // 256
constexpr float FXP = 16777216.0f;    // 2^24

// ---------------- init: pool=0, cf16 convert; block 0 also does graph counts

__global__ void k_init(float* __restrict__ pool, const float* __restrict__ cf,
                       __half* __restrict__ cf16, const int* __restrict__ batch,
                       float* __restrict__ cntf) {
    int i = blockIdx.x * blockDim.x + threadIdx.x;
    if (i < N_GRAPH * O_DIM) pool[i] = 0.0f;
    if (i < V_SIZE * F_IN) cf16[i] = __float2half(cf[i]);
    int i2 = i + N_NODES;
    if (i2 < V_SIZE * F_IN) cf16[i2] = __float2half(cf[i2]);
    if (blockIdx.x == 0) {
        // batch_index is sorted: counts via binary search, no atomics
        int g = threadIdx.x;
        int lo = 0, hi = N_NODES;
        while (lo < hi) { int m = (lo + hi) >> 1; if (batch[m] < g) lo = m + 1; else hi = m; }
        int start = lo;
        lo = 0; hi = N_NODES;
        while (lo < hi) { int m = (lo + hi) >> 1; if (batch[m] <= g) lo = m + 1; else hi = m; }
        cntf[g] = (float)(lo - start);
    }
}

// ---------------- stage A: per-block bucket histogram (LDS) ----------------

__global__ void k_hist(const int* __restrict__ col, int* __restrict__ hist) {
    __shared__ int h[256];
    int t = threadIdx.x;
    h[t] = 0;
    __syncthreads();
    int base = blockIdx.x * EPB;
    #pragma unroll
    for (int i = 0; i < EPB / 256; ++i)
        atomicAdd(&h[col[base + i * 256 + t] >> 8], 1);
    __syncthreads();
    hist[t * NBLK + blockIdx.x] = h[t];   // bucket-major for the scan
}

// ---------------- scan (partial per-256-chunk + block sums) ----------------
// scan3 folded into k_part/k_build via bsum[] lookups.

__global__ void k_scan1(const int* __restrict__ in, int* __restrict__ out,
                        int* __restrict__ bsum) {
    __shared__ int s[256];
    int tid = threadIdx.x;
    int i = blockIdx.x * 256 + tid;
    int v = in[i];
    s[tid] = v;
    __syncthreads();
    for (int d = 1; d < 256; d <<= 1) {
        int t = (tid >= d) ? s[tid - d] : 0;
        __syncthreads();
        s[tid] += t;
        __syncthreads();
    }
    out[i] = s[tid] - v;
    if (tid == 255) bsum[blockIdx.x] = s[255];
}

__global__ void k_scan2(int* __restrict__ bsum) {
    __shared__ int s[256];
    int tid = threadIdx.x;
    int v = bsum[tid];
    s[tid] = v;
    __syncthreads();
    for (int d = 1; d < 256; d <<= 1) {
        int t = (tid >= d) ? s[tid - d] : 0;
        __syncthreads();
        s[tid] += t;
        __syncthreads();
    }
    bsum[tid] = s[tid] - v;
}

// ---------------- stage C: partition into int2 records (LDS cursors) --------
// rec.x = src:16 | dst8:8 | vocab_hi:8 ; rec.y = vocab_lo:2<<16 | ew_fp16:16

__global__ void k_part(const int* __restrict__ row, const int* __restrict__ col,
                       const float* __restrict__ ew, const int* __restrict__ nidx,
                       const int* __restrict__ hoffs, const int* __restrict__ bsum,
                       int2* __restrict__ part) {
    __shared__ int cur[256];
    int t = threadIdx.x;
    cur[t] = hoffs[t * NBLK + blockIdx.x] + bsum[t];
    __syncthreads();
    int base = blockIdx.x * EPB;
    for (int i = 0; i < EPB / 256; ++i) {
        int e = base + i * 256 + t;
        int r = row[e], c = col[e];
        unsigned hw = (unsigned)__half_as_ushort(__float2half(ew[e]));
        int vb = nidx[r];
        int slot = atomicAdd(&cur[c >> 8], 1);
        int2 rec;
        rec.x = (r << 16) | ((c & 255) << 8) | (vb >> 2);
        rec.y = (int)(((unsigned)(vb & 3) << 16) | hw);
        part[slot] = rec;
    }
}

// ---------------- stage D: per-bucket deg/dis + offs + final CSR ------------
// csr.x = src<<10 | vocab ; csr.y = raw ew; k_nrm pre-scales by dis[src].

__global__ void k_build(const int* __restrict__ hoffs, const int* __restrict__ bsum,
                        const int2* __restrict__ part, int2* __restrict__ csr,
                        float* __restrict__ dis, int* __restrict__ offs) {
    __shared__ unsigned long long dc[256];
    __shared__ int sc[256];
    __shared__ int cur[256];
    int t = threadIdx.x;
    int bucket = blockIdx.x;
    dc[t] = 0ULL;
    __syncthreads();
    int start = hoffs[bucket * NBLK] + bsum[bucket];
    int end   = (bucket == 255) ? N_EDGES : (hoffs[(bucket + 1) * NBLK] + bsum[bucket + 1]);
    for (int j = start + t; j < end; j += 256) {
        int2 rec = part[j];
        int dst = (rec.x >> 8) & 255;
        float w = __half2float(__ushort_as_half((unsigned short)(rec.y & 0xFFFF)));
        unsigned long long add = (1ULL << 40) |
            (unsigned long long)(unsigned)(w * FXP + 0.5f);
        atomicAdd(&dc[dst], add);
    }
    __syncthreads();
    unsigned long long v = dc[t];
    float deg = 1.0f + (float)(v & 0xFFFFFFFFFFULL) * (1.0f / FXP);   // self-loop +1
    dis[bucket * 256 + t] = 1.0f / sqrtf(deg);                        // deg >= 1
    int cnt = (int)(v >> 40);
    sc[t] = cnt;
    __syncthreads();
    for (int d = 1; d < 256; d <<= 1) {
        int x = (t >= d) ? sc[t - d] : 0;
        __syncthreads();
        sc[t] += x;
        __syncthreads();
    }
    int node_off = start + sc[t] - cnt;
    offs[bucket * 256 + t] = node_off;
    cur[t] = node_off;
    if (bucket == 255 && t == 255) offs[N_NODES] = N_EDGES;
    __syncthreads();
    for (int j = start + t; j < end; j += 256) {
        int2 rec = part[j];
        int dst = (rec.x >> 8) & 255;
        unsigned src = ((unsigned)rec.x) >> 16;
        int vb = ((rec.x & 255) << 2) | ((rec.y >> 16) & 3);
        float w = __half2float(__ushort_as_half((unsigned short)(rec.y & 0xFFFF)));
        int slot = atomicAdd(&cur[dst], 1);
        int2 e;
        e.x = (int)((src << 10) | (unsigned)vb);
        e.y = __float_as_int(w);
        csr[slot] = e;
    }
}

// ---------------- nrm transform: csr.y = dis[src] * ew ----------------
// (dis[dst] factors out and is applied in the agg kernels)

__global__ void k_nrm(int2* __restrict__ csr, const float* __restrict__ dis) {
    int i = blockIdx.x * blockDim.x + threadIdx.x;
    int2 e = csr[i];
    e.y = __float_as_int(dis[e.x >> 10] * __int_as_float(e.y));
    csr[i] = e;
}

// ---------------- layer-1 aggregation (wave per node, unroll 8) --------------

__global__ void k_agg0(const __half2* __restrict__ cf16, const int* __restrict__ nidx,
                       const float* __restrict__ dis, const int* __restrict__ offs,
                       const int2* __restrict__ csr, float2* __restrict__ aggX) {
    int wave = threadIdx.x >> 6;
    int lane = threadIdx.x & 63;
    int c = blockIdx.x * 4 + wave;
    float d = dis[c];
    float2 self = __half22float2(cf16[(size_t)nidx[c] * 64 + lane]);
    float2 esum = {0.f, 0.f};
    int s0 = offs[c], s1 = offs[c + 1];
    int s = s0;
    for (; s + 8 <= s1; s += 8) {
        int2 e[8];
        #pragma unroll
        for (int u = 0; u < 8; ++u) e[u] = csr[s + u];
        float2 v[8];
        #pragma unroll
        for (int u = 0; u < 8; ++u)
            v[u] = __half22float2(cf16[(size_t)(e[u].x & 1023) * 64 + lane]);
        #pragma unroll
        for (int u = 0; u < 8; ++u) {
            float n = __int_as_float(e[u].y);
            esum.x += v[u].x * n; esum.y += v[u].y * n;
        }
    }
    for (; s < s1; ++s) {
        int2 e0 = csr[s];
        float2 v0 = __half22float2(cf16[(size_t)(e0.x & 1023) * 64 + lane]);
        float n0 = __int_as_float(e0.y);
        esum.x += v0.x * n0; esum.y += v0.y * n0;
    }
    float dd = d * d;
    float2 acc;
    acc.x = self.x * dd + d * esum.x;
    acc.y = self.y * dd + d * esum.y;
    aggX[(size_t)c * 64 + lane] = acc;
}

// ---------------- GEMM1: aggX [N,128] @ W1 + b1, relu -> h1 [N,256] ----------

__global__ void k_gemm1(const float* __restrict__ aggX, const float* __restrict__ W1,
                        const float* __restrict__ b1, float* __restrict__ h1) {
    __shared__ float xs[32 * F_IN];   // 16 KB
    int nb = blockIdx.x * 32;
    int t  = threadIdx.x;
    const float4* src = (const float4*)(aggX + (size_t)nb * F_IN);
    float4* dst = (float4*)xs;
    #pragma unroll
    for (int p = 0; p < 4; ++p) dst[p * 256 + t] = src[p * 256 + t];
    __syncthreads();
    int o  = t & 63;
    int jg = t >> 6;
    const float* xsj = xs + jg * 8 * F_IN;
    float acc[8][4] = {};
    for (int k = 0; k < F_IN; ++k) {
        float w0 = W1[k * H_DIM + o];
        float w1 = W1[k * H_DIM + o + 64];
        float w2 = W1[k * H_DIM + o + 128];
        float w3 = W1[k * H_DIM + o + 192];
        #pragma unroll
        for (int j = 0; j < 8; ++j) {
            float x = xsj[j * F_IN + k];
            acc[j][0] += x * w0; acc[j][1] += x * w1;
            acc[j][2] += x * w2; acc[j][3] += x * w3;
        }
    }
    float bb0 = b1[o], bb1 = b1[o + 64], bb2 = b1[o + 128], bb3 = b1[o + 192];
    #pragma unroll
    for (int j = 0; j < 8; ++j) {
        size_t base = (size_t)(nb + jg * 8 + j) * H_DIM + o;
        float v0 = acc[j][0] + bb0, v1 = acc[j][1] + bb1;
        float v2 = acc[j][2] + bb2, v3 = acc[j][3] + bb3;
        h1[base]       = v0 > 0.f ? v0 : 0.f;
        h1[base + 64]  = v1 > 0.f ? v1 : 0.f;
        h1[base + 128] = v2 > 0.f ? v2 : 0.f;
        h1[base + 192] = v3 > 0.f ? v3 : 0.f;
    }
}

// ---------------- GEMM2: h1 [N,256] @ W2 -> xw2 (fp16) [N,128] ---------------

__global__ void k_gemm2(const float* __restrict__ h1, const float* __restrict__ W2,
                        __half* __restrict__ xw2h) {
    __shared__ float xs[32 * H_DIM];  // 32 KB
    int nb = blockIdx.x * 32;
    int t  = threadIdx.x;
    const float4* src = (const float4*)(h1 + (size_t)nb * H_DIM);
    float4* dst = (float4*)xs;
    #pragma unroll
    for (int p = 0; p < 8; ++p) dst[p * 256 + t] = src[p * 256 + t];
    __syncthreads();
    int o  = t & 63;
    int jg = t >> 6;
    const float* xsj = xs + jg * 8 * H_DIM;
    float acc[8][2] = {};
    for (int k = 0; k < H_DIM; ++k) {
        float w0 = W2[k * O_DIM + o];
        float w1 = W2[k * O_DIM + o + 64];
        #pragma unroll
        for (int j = 0; j < 8; ++j) {
            float x = xsj[j * H_DIM + k];
            acc[j][0] += x * w0; acc[j][1] += x * w1;
        }
    }
    #pragma unroll
    for (int j = 0; j < 8; ++j) {
        size_t base = (size_t)(nb + jg * 8 + j) * O_DIM + o;
        xw2h[base]      = __float2half(acc[j][0]);
        xw2h[base + 64] = __float2half(acc[j][1]);
    }
}

// ---------------- layer-2 agg + relu + LDS-reduced pool (4 nodes/block) ------

__global__ void k_agg2_pool(const __half2* __restrict__ xw2h, const float* __restrict__ b2,
                            const float* __restrict__ dis, const int* __restrict__ offs,
                            const int2* __restrict__ csr, const int* __restrict__ batch,
                            float* __restrict__ pool) {
    __shared__ float2 red[4][64];
    __shared__ int bgs[4];
    int wave = threadIdx.x >> 6;
    int lane = threadIdx.x & 63;
    int c = blockIdx.x * 4 + wave;
    float d = dis[c];
    float2 self = __half22float2(xw2h[(size_t)c * 64 + lane]);
    float2 bb = ((const float2*)b2)[lane];
    float2 esum = {0.f, 0.f};
    int s0 = offs[c], s1 = offs[c + 1];
    int s = s0;
    for (; s + 8 <= s1; s += 8) {
        int2 e[8];
        #pragma unroll
        for (int u = 0; u < 8; ++u) e[u] = csr[s + u];
        float2 v[8];
        #pragma unroll
        for (int u = 0; u < 8; ++u)
            v[u] = __half22float2(xw2h[(size_t)(e[u].x >> 10) * 64 + lane]);
        #pragma unroll
        for (int u = 0; u < 8; ++u) {
            float n = __int_as_float(e[u].y);
            esum.x += v[u].x * n; esum.y += v[u].y * n;
        }
    }
    for (; s < s1; ++s) {
        int2 e0 = csr[s];
        float2 v0 = __half22float2(xw2h[(size_t)(e0.x >> 10) * 64 + lane]);
        float n0 = __int_as_float(e0.y);
        esum.x += v0.x * n0; esum.y += v0.y * n0;
    }
    float dd = d * d;
    float2 acc;
    acc.x = bb.x + self.x * dd + d * esum.x;
    acc.y = bb.y + self.y * dd + d * esum.y;
    acc.x = acc.x > 0.0f ? acc.x : 0.0f;
    acc.y = acc.y > 0.0f ? acc.y : 0.0f;
    red[wave][lane] = acc;
    if (lane == 0) bgs[wave] = batch[c];
    __syncthreads();
    if (wave == 0) {
        float2 a = red[0][lane];
        int cg = bgs[0];
        #pragma unroll
        for (int w = 1; w < 4; ++w) {
            int g = bgs[w];
            float2 r = red[w][lane];
            if (g == cg) { a.x += r.x; a.y += r.y; }
            else {
                atomicAdd(&pool[cg * O_DIM + 2 * lane], a.x);
                atomicAdd(&pool[cg * O_DIM + 2 * lane + 1], a.y);
                a = r; cg = g;
            }
        }
        atomicAdd(&pool[cg * O_DIM + 2 * lane], a.x);
        atomicAdd(&pool[cg * O_DIM + 2 * lane + 1], a.y);
    }
}

__global__ void k_final(const float* __restrict__ pool, const float* __restrict__ cnt,
                        float* __restrict__ out) {
    int t = blockIdx.x * blockDim.x + threadIdx.x;
    if (t < N_GRAPH * O_DIM) {
        int g = t / O_DIM;
        out[t] = pool[t] / fmaxf(cnt[g], 1.0f);
    }
}

// ---------------- launch ----------------

extern "C" void kernel_launch(void* const* d_in, const int* in_sizes, int n_in,
                              void* d_out, int out_size, void* d_ws, size_t ws_size,
                              hipStream_t stream) {
    const float* cf   = (const float*)d_in[0];   // [V,128]
    const float* W1   = (const float*)d_in[1];   // [128,256]
    const float* b1   = (const float*)d_in[2];   // [256]
    const float* W2   = (const float*)d_in[3];   // [256,128]
    const float* b2   = (const float*)d_in[4];   // [128]
    const float* ew   = (const float*)d_in[5];   // [E]
    const int*   nidx = (const int*)d_in[6];     // [N]
    const int*   eidx = (const int*)d_in[7];     // [2,E]
    const int*   bidx = (const int*)d_in[8];     // [N]
    float* out = (float*)d_out;

    const int* row = eidx;            // source
    const int* col = eidx + N_EDGES;  // target

    // workspace layout (bytes)
    char* ws = (char*)d_ws;
    size_t off = 0;
    int*   hist  = (int*)  (ws + off); off += (size_t)N_NODES * 4;          // 256K
    int*   hoffs = (int*)  (ws + off); off += (size_t)N_NODES * 4;          // 256K
    int*   bsum  = (int*)  (ws + off); off += 4096;
    float* dis   = (float*)(ws + off); off += (size_t)N_NODES * 4;          // 256K
    int*   offs  = (int*)  (ws + off); off += (size_t)(N_NODES + 16) * 4;   // 256K
    int2*  csr   = (int2*) (ws + off); off += (size_t)N_EDGES * 8;          // 16M
    float* pool  = (float*)(ws + off); off += (size_t)(N_GRAPH * O_DIM + N_GRAPH) * 4;
    __half* cf16 = (__half*)(ws + off); off += (size_t)V_SIZE * F_IN * 2;   // 256K
    off = (off + 255) & ~(size_t)255;
    float* aggX  = (float*)(ws + off); off += (size_t)N_NODES * F_IN * 4;   // 32M
    float* h1    = (float*)(ws + off);                                      // 64M
    int2*  part  = (int2*)aggX;      // 16M bucket buffer, dead before k_agg0
    __half* xw2h = (__half*)aggX;    // aggX dead after gemm1
    float* cntf  = pool + N_GRAPH * O_DIM;

    // 1. init (+gcount in block 0) + bucket histogram + 2-stage scan
    k_init<<<N_NODES / 256, 256, 0, stream>>>(pool, cf, cf16, bidx, cntf);
    k_hist<<<NBLK, 256, 0, stream>>>(col, hist);
    k_scan1<<<256, 256, 0, stream>>>(hist, hoffs, bsum);
    k_scan2<<<1, 256, 0, stream>>>(bsum);

    // 2. partition (int2 recs) -> per-bucket build -> nrm pre-scale
    k_part<<<NBLK, 256, 0, stream>>>(row, col, ew, nidx, hoffs, bsum, part);
    k_build<<<256, 256, 0, stream>>>(hoffs, bsum, part, csr, dis, offs);
    k_nrm<<<N_EDGES / 256, 256, 0, stream>>>(csr, dis);

    // 3. layer 1: aggregate fp16 features (wave/node), then GEMM (+b1, relu)
    k_agg0<<<N_NODES / 4, 256, 0, stream>>>((const __half2*)cf16, nidx, dis, offs, csr,
                                            (float2*)aggX);
    k_gemm1<<<N_NODES / 32, 256, 0, stream>>>(aggX, W1, b1, h1);

    // 4. layer 2: GEMM -> fp16, aggregate + relu + LDS-reduced pool
    k_gemm2<<<N_NODES / 32, 256, 0, stream>>>(h1, W2, xw2h);
    k_agg2_pool<<<N_NODES / 4, 256, 0, stream>>>((const __half2*)xw2h, b2, dis, offs, csr,
                                                 bidx, pool);

    // 5. final divide
    k_final<<<(N_GRAPH * O_DIM + 255) / 256, 256, 0, stream>>>(pool, cntf, out);
}